// Round 1
// 2343.718 us; speedup vs baseline: 1.0044x; 1.0044x over previous
//
#include <hip/hip_runtime.h>
#include <hip/hip_bf16.h>

// CGCNN: 3x CGConv + projection + mean-pool + 2-layer MLP.
// Round 7: agg_fused — force the per-wave edge-weight cache (wf[32]/ws[32])
// to be VGPR-resident via opaque asm pins. Round 6 intended a 64-VGPR cache
// but rocprof showed VGPR_Count=48: the compiler rematerialized the weight
// loads inside the inner loop (~3x VALU issue vs the 64 useful FMAs/edge).
// Also: node_gemm grid swapped so the 8 col-sections of one m-tile run
// back-to-back (h tile stays in L2; was 8 full sweeps of 51MB).

#define N_NODES 100000
#define N_EDGES 1600000
#define HID 128
#define SCAN_BLOCKS 391  // ceil(100000/256)
#define AGGF_BLOCKS 8192

typedef unsigned int uint;

__device__ inline float bflo(uint u) { return __uint_as_float(u << 16); }
__device__ inline float bfhi(uint u) { return __uint_as_float(u & 0xffff0000u); }
// parity-select: shamt = 16 for low half (even ch), 0 for high half (odd ch)
__device__ inline float bfsel(uint u, uint shamt) {
  return __uint_as_float((u << shamt) & 0xffff0000u);
}
__device__ inline uint pack_bf16_2(float a, float b) {
  uint ua = __float_as_uint(a), ub = __float_as_uint(b);
  ua = (ua + 0x7fffu + ((ua >> 16) & 1u)) >> 16;
  ub = (ub + 0x7fffu + ((ub >> 16) & 1u)) >> 16;
  return ua | (ub << 16);
}
__device__ inline float sigmoidf_(float x) {
  return __builtin_amdgcn_rcpf(1.f + __expf(-x));
}
__device__ inline float softplusf_(float x) {
  return fmaxf(x, 0.f) + __logf(1.f + __expf(-fabsf(x)));
}

// ---------------- CSR build ----------------
__global__ __launch_bounds__(256) void hist_k(const int* __restrict__ ei,
                                              int* __restrict__ deg) {
  int e = blockIdx.x * 256 + threadIdx.x;
  if (e >= N_EDGES) return;
  atomicAdd(&deg[ei[N_EDGES + e]], 1);
}

__global__ __launch_bounds__(256) void scan1_k(const int* __restrict__ deg,
                                               int* __restrict__ rowptr,
                                               int* __restrict__ bsums) {
  __shared__ int s[256];
  int i = blockIdx.x * 256 + threadIdx.x;
  int v = (i < N_NODES) ? deg[i] : 0;
  s[threadIdx.x] = v;
  __syncthreads();
  for (int off = 1; off < 256; off <<= 1) {
    int t = (threadIdx.x >= off) ? s[threadIdx.x - off] : 0;
    __syncthreads();
    s[threadIdx.x] += t;
    __syncthreads();
  }
  if (i < N_NODES) rowptr[i] = s[threadIdx.x] - v;  // exclusive
  if (threadIdx.x == 255) bsums[blockIdx.x] = s[255];
}

__global__ __launch_bounds__(512) void scan2_k(int* __restrict__ bsums) {
  __shared__ int s[512];
  int t = threadIdx.x;
  int v = (t < SCAN_BLOCKS) ? bsums[t] : 0;
  s[t] = v;
  __syncthreads();
  for (int off = 1; off < 512; off <<= 1) {
    int x = (t >= off) ? s[t - off] : 0;
    __syncthreads();
    s[t] += x;
    __syncthreads();
  }
  if (t < SCAN_BLOCKS) bsums[t] = s[t] - v;  // exclusive
}

__global__ __launch_bounds__(256) void scan3_k(int* __restrict__ rowptr,
                                               const int* __restrict__ bsums,
                                               int* __restrict__ cur) {
  int i = blockIdx.x * 256 + threadIdx.x;
  if (i < N_NODES) {
    int r = rowptr[i] + bsums[blockIdx.x];
    rowptr[i] = r;
    cur[i] = r;
  }
  if (i == 0) rowptr[N_NODES] = N_EDGES;
}

__global__ __launch_bounds__(256) void scatter_k(const int* __restrict__ ei,
                                                 int* __restrict__ cur,
                                                 uint2* __restrict__ csr) {
  int e = blockIdx.x * 256 + threadIdx.x;
  if (e >= N_EDGES) return;
  int d = ei[N_EDGES + e];
  int pos = atomicAdd(&cur[d], 1);
  csr[pos] = make_uint2((uint)ei[e], (uint)e);
}

// ---------------- conv1 (channels=3) ----------------
__global__ __launch_bounds__(256) void conv1_edge(
    const float* __restrict__ x, const int* __restrict__ ei,
    const float* __restrict__ ea,
    const float* __restrict__ Wf, const float* __restrict__ bf,
    const float* __restrict__ Ws, const float* __restrict__ bs,
    float* __restrict__ agg1) {
  int e = blockIdx.x * 256 + threadIdx.x;
  if (e >= N_EDGES) return;
  int src = ei[e], dst = ei[N_EDGES + e];
  float z[38];
#pragma unroll
  for (int k = 0; k < 3; ++k) z[k] = x[dst * 3 + k];
#pragma unroll
  for (int k = 0; k < 3; ++k) z[3 + k] = x[src * 3 + k];
  const float4* er4 = (const float4*)(ea + (long long)e * 32);
#pragma unroll
  for (int k = 0; k < 8; ++k) {
    float4 v = er4[k];
    z[6 + 4 * k + 0] = v.x;
    z[6 + 4 * k + 1] = v.y;
    z[6 + 4 * k + 2] = v.z;
    z[6 + 4 * k + 3] = v.w;
  }
#pragma unroll
  for (int c = 0; c < 3; ++c) {
    float f = bf[c], s = bs[c];
#pragma unroll
    for (int k = 0; k < 38; ++k) {
      f = fmaf(z[k], Wf[k * 3 + c], f);
      s = fmaf(z[k], Ws[k * 3 + c], s);
    }
    atomicAdd(&agg1[dst * 3 + c], sigmoidf_(f) * softplusf_(s));
  }
}

// ---------------- projection: h = relu((x+agg1) @ Wp + bp) ----------------
__global__ __launch_bounds__(256) void proj_kernel(
    const float* __restrict__ x, const float* __restrict__ agg1,
    const float* __restrict__ Wp, const float* __restrict__ bp,
    float* __restrict__ h) {
  long long i = (long long)blockIdx.x * 256 + threadIdx.x;
  if (i >= (long long)N_NODES * HID) return;
  int n = (int)(i >> 7), j = (int)(i & 127);
  float v0 = x[n * 3 + 0] + agg1[n * 3 + 0];
  float v1 = x[n * 3 + 1] + agg1[n * 3 + 1];
  float v2 = x[n * 3 + 2] + agg1[n * 3 + 2];
  float acc = bp[j];
  acc = fmaf(v0, Wp[0 * HID + j], acc);
  acc = fmaf(v1, Wp[1 * HID + j], acc);
  acc = fmaf(v2, Wp[2 * HID + j], acc);
  h[i] = fmaxf(acc, 0.f);
}

// ---------------- node transform GEMM -> bf16 Pb ----------------
// Pb[n] (512 bf16): [ f_dst(128) | s_dst(128) | f_src(128) | s_src(128) ]
// Grid: x = col-section (8, fast) so one m-tile's 8 sections run
// back-to-back and the h tile stays in L2; y = m-tile (1563).
#define BM 64
#define BK 32
__global__ __launch_bounds__(256) void node_gemm(
    const float* __restrict__ h, const float* __restrict__ Wf,
    const float* __restrict__ Ws, uint* __restrict__ Pb) {
  __shared__ float As[BK][BM + 4];
  __shared__ float Bs[BK][BM + 4];
  int jblk = blockIdx.x;
  int sec = jblk >> 1;
  int colbase = (jblk & 1) * 64;
  const float* W = (sec == 0 || sec == 2) ? Wf : Ws;
  int rowoff = (sec >= 2) ? 128 : 0;
  int m0 = blockIdx.y * BM;
  int tid = threadIdx.x;
  int tx = tid & 15, ty = tid >> 4;
  float acc[4][4] = {};
  for (int k0 = 0; k0 < 128; k0 += BK) {
#pragma unroll
    for (int i = 0; i < 2; ++i) {
      int f = tid + i * 256;
      int r = f >> 3, c4 = (f & 7) * 4;
      float4 v = {0.f, 0.f, 0.f, 0.f};
      int row = m0 + r;
      if (row < N_NODES)
        v = *(const float4*)&h[(long long)row * 128 + k0 + c4];
      As[c4 + 0][r] = v.x; As[c4 + 1][r] = v.y;
      As[c4 + 2][r] = v.z; As[c4 + 3][r] = v.w;
    }
#pragma unroll
    for (int i = 0; i < 2; ++i) {
      int f = tid + i * 256;
      int r = f >> 4, c4 = (f & 15) * 4;
      float4 v = *(const float4*)&W[(long long)(k0 + r + rowoff) * 128 + colbase + c4];
      *(float4*)&Bs[r][c4] = v;
    }
    __syncthreads();
#pragma unroll
    for (int k = 0; k < BK; ++k) {
      float4 a = *(const float4*)&As[k][ty * 4];
      float4 b = *(const float4*)&Bs[k][tx * 4];
      float av[4] = {a.x, a.y, a.z, a.w};
      float bv[4] = {b.x, b.y, b.z, b.w};
#pragma unroll
      for (int i = 0; i < 4; ++i)
#pragma unroll
        for (int j = 0; j < 4; ++j)
          acc[i][j] = fmaf(av[i], bv[j], acc[i][j]);
    }
    __syncthreads();
  }
#pragma unroll
  for (int i = 0; i < 4; ++i) {
    int row = m0 + ty * 4 + i;
    if (row < N_NODES) {
      uint2 o;
      o.x = pack_bf16_2(acc[i][0], acc[i][1]);
      o.y = pack_bf16_2(acc[i][2], acc[i][3]);
      *(uint2*)&Pb[(long long)row * 256 + jblk * 32 + tx * 2] = o;
    }
  }
}

// -------- fused CSR aggregation v3: VGPR-pinned weight cache --------
// 2 waves/node, 64 ch per wave. Weight cache = 64 floats/wave, pinned
// into VGPRs with opaque asm so the compiler cannot rematerialize the
// loads inside the edge loop (Round 6 shipped with VGPR_Count=48 ⇒ the
// cache was being re-fetched per edge). 2-edge groups for ILP; ea rows
// load via SMEM (wave-uniform address from readfirstlane).
__global__ __launch_bounds__(256, 4) void agg_fused(
    const uint* __restrict__ Pb, const float* __restrict__ ea,
    const float* __restrict__ Wf, const float* __restrict__ Ws,
    const float* __restrict__ bf, const float* __restrict__ bs,
    const int* __restrict__ rowptr, const uint2* __restrict__ csr,
    float* __restrict__ h) {
  int wave = threadIdx.x >> 6;
  int lane = threadIdx.x & 63;
  int c = ((wave & 1) << 6) + lane;  // channel 0..127
  int nodeSlot = wave >> 1;          // 0..1
  float wf[32], ws[32];
#pragma unroll
  for (int k = 0; k < 32; ++k) {
    wf[k] = Wf[(256 + k) * HID + c];
    ws[k] = Ws[(256 + k) * HID + c];
  }
  // Pin the weight cache: opaque asm makes each value unrematerializable,
  // forcing 64 live VGPRs (fits: ~110 total < 128 cap from launch_bounds).
#pragma unroll
  for (int k = 0; k < 32; ++k) {
    asm volatile("" : "+v"(wf[k]));
    asm volatile("" : "+v"(ws[k]));
  }
  float bfc = bf[c], bsc = bs[c];
  int dw = c >> 1;                       // dword index within 64-dword region
  uint shamt = (c & 1) ? 0u : 16u;       // bf16 half select
  for (int node = blockIdx.x * 2 + nodeSlot; node < N_NODES;
       node += gridDim.x * 2) {
    int row0 = rowptr[node], row1 = rowptr[node + 1];
    const uint* Pd = Pb + (long long)node * 256;
    uint fdu = Pd[dw], sdu = Pd[64 + dw];
    float fd = bfsel(fdu, shamt) + bfc;
    float sd = bfsel(sdu, shamt) + bsc;
    float a = 0.f;
    int j = row0;
    for (; j + 1 < row1; j += 2) {
      uint2 m0 = csr[j], m1 = csr[j + 1];
      int sA = __builtin_amdgcn_readfirstlane((int)m0.x);
      int eA = __builtin_amdgcn_readfirstlane((int)m0.y);
      int sB = __builtin_amdgcn_readfirstlane((int)m1.x);
      int eB = __builtin_amdgcn_readfirstlane((int)m1.y);
      const float* erA = ea + (long long)eA * 32;
      const float* erB = ea + (long long)eB * 32;
      const uint* PsA = Pb + (long long)sA * 256;
      const uint* PsB = Pb + (long long)sB * 256;
      uint fsuA = PsA[128 + dw], ssuA = PsA[192 + dw];
      uint fsuB = PsB[128 + dw], ssuB = PsB[192 + dw];
      float efA = 0.f, esA = 0.f, efB = 0.f, esB = 0.f;
#pragma unroll
      for (int k = 0; k < 32; ++k) {
        float evA = erA[k], evB = erB[k];
        efA = fmaf(evA, wf[k], efA);
        esA = fmaf(evA, ws[k], esA);
        efB = fmaf(evB, wf[k], efB);
        esB = fmaf(evB, ws[k], esB);
      }
      float fA = fd + bfsel(fsuA, shamt) + efA;
      float gA = sd + bfsel(ssuA, shamt) + esA;
      float fB = fd + bfsel(fsuB, shamt) + efB;
      float gB = sd + bfsel(ssuB, shamt) + esB;
      a += sigmoidf_(fA) * softplusf_(gA);
      a += sigmoidf_(fB) * softplusf_(gB);
    }
    if (j < row1) {
      uint2 m0 = csr[j];
      int sA = __builtin_amdgcn_readfirstlane((int)m0.x);
      int eA = __builtin_amdgcn_readfirstlane((int)m0.y);
      const float* erA = ea + (long long)eA * 32;
      const uint* PsA = Pb + (long long)sA * 256;
      uint fsuA = PsA[128 + dw], ssuA = PsA[192 + dw];
      float efA = 0.f, esA = 0.f;
#pragma unroll
      for (int k = 0; k < 32; ++k) {
        float evA = erA[k];
        efA = fmaf(evA, wf[k], efA);
        esA = fmaf(evA, ws[k], esA);
      }
      float fA = fd + bfsel(fsuA, shamt) + efA;
      float gA = sd + bfsel(ssuA, shamt) + esA;
      a += sigmoidf_(fA) * softplusf_(gA);
    }
    float* hp = &h[(long long)node * HID + c];
    *hp = fmaxf(*hp + a, 0.f);
  }
}

// -------- segmented mean pool (batch sorted; ~2 flushes per block) --------
#define POOL_NODES 128
__global__ __launch_bounds__(128) void pool2(
    const float* __restrict__ h, const int* __restrict__ batch,
    float* __restrict__ sums, float* __restrict__ cnts) {
  int n0 = blockIdx.x * POOL_NODES;
  if (n0 >= N_NODES) return;
  int t = threadIdx.x;
  int nEnd = n0 + POOL_NODES;
  if (nEnd > N_NODES) nEnd = N_NODES;
  float acc = 0.f;
  int bcur = batch[n0];
  int cnt = 0;
  for (int n = n0; n < nEnd; ++n) {
    int b = batch[n];
    if (b != bcur) {
      atomicAdd(&sums[bcur * HID + t], acc);
      if (t == 0) atomicAdd(&cnts[bcur], (float)cnt);
      acc = 0.f; cnt = 0; bcur = b;
    }
    acc += h[(long long)n * HID + t];
    ++cnt;
  }
  atomicAdd(&sums[bcur * HID + t], acc);
  if (t == 0) atomicAdd(&cnts[bcur], (float)cnt);
}

// ---------------- graph MLP ----------------
__global__ __launch_bounds__(128) void mlpA(
    const float* __restrict__ sums, const float* __restrict__ cnts,
    const float* __restrict__ W1, const float* __restrict__ b1,
    float* __restrict__ g) {
  __shared__ float pl[HID];
  int gr = blockIdx.x, j = threadIdx.x;
  float cnt = fmaxf(cnts[gr], 1.f);
  pl[j] = sums[gr * HID + j] / cnt;
  __syncthreads();
  float acc = b1[j];
#pragma unroll 8
  for (int k = 0; k < HID; ++k) acc = fmaf(pl[k], W1[k * HID + j], acc);
  g[gr * HID + j] = fmaxf(acc, 0.f);
}

__global__ __launch_bounds__(256) void mlpB(
    const float* __restrict__ g, const float* __restrict__ W2,
    const float* __restrict__ b2, float* __restrict__ out) {
  int t = threadIdx.x;
  if (t >= 64 * 3) return;
  int gr = t / 3, o = t % 3;
  float acc = b2[o];
#pragma unroll 8
  for (int k = 0; k < HID; ++k) acc = fmaf(g[gr * HID + k], W2[k * 3 + o], acc);
  out[t] = acc;
}

extern "C" void kernel_launch(void* const* d_in, const int* in_sizes, int n_in,
                              void* d_out, int out_size, void* d_ws, size_t ws_size,
                              hipStream_t stream) {
  const float* x   = (const float*)d_in[0];
  const int*   ei  = (const int*)d_in[1];
  const float* ea  = (const float*)d_in[2];
  const int*   bat = (const int*)d_in[3];
  const float* Wf1 = (const float*)d_in[4];
  const float* bf1 = (const float*)d_in[5];
  const float* Ws1 = (const float*)d_in[6];
  const float* bs1 = (const float*)d_in[7];
  const float* Wp  = (const float*)d_in[8];
  const float* bp  = (const float*)d_in[9];
  const float* Wf2 = (const float*)d_in[10];
  const float* bf2 = (const float*)d_in[11];
  const float* Ws2 = (const float*)d_in[12];
  const float* bs2 = (const float*)d_in[13];
  const float* Wf3 = (const float*)d_in[14];
  const float* bf3 = (const float*)d_in[15];
  const float* Ws3 = (const float*)d_in[16];
  const float* bs3 = (const float*)d_in[17];
  const float* W1  = (const float*)d_in[18];
  const float* b1  = (const float*)d_in[19];
  const float* W2  = (const float*)d_in[20];
  const float* b2  = (const float*)d_in[21];
  float* out = (float*)d_out;

  char* w = (char*)d_ws;
  size_t off = 0;
  auto alloc = [&](size_t bytes) {
    void* p = w + off;
    off += (bytes + 255) & ~(size_t)255;
    return p;
  };
  int*   deg    = (int*)alloc((size_t)N_NODES * 4);
  int*   rowptr = (int*)alloc((size_t)(N_NODES + 1) * 4);
  int*   cur    = (int*)alloc((size_t)N_NODES * 4);
  int*   bsums  = (int*)alloc((size_t)512 * 4);
  uint2* csr    = (uint2*)alloc((size_t)N_EDGES * 8);        // 12.8 MB
  float* agg1   = (float*)alloc((size_t)N_NODES * 3 * 4);    // 1.2 MB
  float* h      = (float*)alloc((size_t)N_NODES * HID * 4);  // 51.2 MB
  uint*  Pb     = (uint*)alloc((size_t)N_NODES * 256 * 4);   // 102.4 MB
  float* sums   = (float*)alloc((size_t)64 * HID * 4);
  float* cnts   = (float*)alloc((size_t)64 * 4);
  float* g      = (float*)alloc((size_t)64 * HID * 4);
  (void)ws_size;  // total ~170 MB

  // ---- CSR build ----
  hipMemsetAsync(deg, 0, (size_t)N_NODES * 4, stream);
  hist_k<<<(N_EDGES + 255) / 256, 256, 0, stream>>>(ei, deg);
  scan1_k<<<SCAN_BLOCKS, 256, 0, stream>>>(deg, rowptr, bsums);
  scan2_k<<<1, 512, 0, stream>>>(bsums);
  scan3_k<<<SCAN_BLOCKS, 256, 0, stream>>>(rowptr, bsums, cur);
  scatter_k<<<(N_EDGES + 255) / 256, 256, 0, stream>>>(ei, cur, csr);

  // ---- conv1 ----
  hipMemsetAsync(agg1, 0, (size_t)N_NODES * 3 * 4, stream);
  conv1_edge<<<(N_EDGES + 255) / 256, 256, 0, stream>>>(x, ei, ea, Wf1, bf1, Ws1, bs1, agg1);
  proj_kernel<<<(N_NODES * HID + 255) / 256, 256, 0, stream>>>(x, agg1, Wp, bp, h);

  // col-sections on x (fast) so the h tile is reused in L2 across sections
  dim3 ngrid(8, (N_NODES + BM - 1) / BM);

  // ---- conv2 ----
  node_gemm<<<ngrid, 256, 0, stream>>>(h, Wf2, Ws2, Pb);
  agg_fused<<<AGGF_BLOCKS, 256, 0, stream>>>(Pb, ea, Wf2, Ws2, bf2, bs2, rowptr, csr, h);

  // ---- conv3 ----
  node_gemm<<<ngrid, 256, 0, stream>>>(h, Wf3, Ws3, Pb);
  agg_fused<<<AGGF_BLOCKS, 256, 0, stream>>>(Pb, ea, Wf3, Ws3, bf3, bs3, rowptr, csr, h);

  // ---- pool + MLP ----
  hipMemsetAsync(sums, 0, (size_t)(64 * HID + 64) * 4, stream);
  pool2<<<(N_NODES + POOL_NODES - 1) / POOL_NODES, POOL_NODES, 0, stream>>>(h, bat, sums, cnts);
  mlpA<<<64, 128, 0, stream>>>(sums, cnts, W1, b1, g);
  mlpB<<<1, 256, 0, stream>>>(g, W2, b2, out);
}

// Round 2
// 2123.187 us; speedup vs baseline: 1.1087x; 1.1039x over previous
//
#include <hip/hip_runtime.h>
#include <hip/hip_bf16.h>

// CGCNN: 3x CGConv + projection + mean-pool + 2-layer MLP.
// Round 8: structural — move the per-edge gate GEMM (ea @ [Wfe|Wse], 26
// GFLOP/layer) off the VALU (which was issue-bound at 94% with MfmaUtil=0
// and an unexplained 2.5x instruction overhead) onto the matrix pipe:
//   node_gemm2: Pb[node] = packed {f,s} bf16 gates (dst | src regions)
//   w_prep:     Btg[256ch][32k] bf16 transposed edge-weight block
//   edge_msg:   per 64-edge CSR tile: MFMA 16x16x32_bf16 edge-gemm + gate
//               add + sigmoid*softplus -> final message m (bf16, packed
//               edge-pairs, CSR order)
//   agg_sum:    trivial coalesced segmented sum of m + relu(h + agg)
// Old VALU path (node_gemm + agg_fused) kept as fallback if ws_size is too
// small for the 410 MB m buffer.

#define N_NODES 100000
#define N_EDGES 1600000
#define HID 128
#define SCAN_BLOCKS 391  // ceil(100000/256)
#define AGGF_BLOCKS 8192

typedef unsigned int uint;
typedef short bf16x8 __attribute__((ext_vector_type(8)));
typedef float f32x4 __attribute__((ext_vector_type(4)));

__device__ inline float bflo(uint u) { return __uint_as_float(u << 16); }
__device__ inline float bfhi(uint u) { return __uint_as_float(u & 0xffff0000u); }
__device__ inline float bfsel(uint u, uint shamt) {
  return __uint_as_float((u << shamt) & 0xffff0000u);
}
__device__ inline uint pack_bf16_2(float a, float b) {
  uint ua = __float_as_uint(a), ub = __float_as_uint(b);
  ua = (ua + 0x7fffu + ((ua >> 16) & 1u)) >> 16;
  ub = (ub + 0x7fffu + ((ub >> 16) & 1u)) >> 16;
  return ua | (ub << 16);
}
__device__ inline float sigmoidf_(float x) {
  return __builtin_amdgcn_rcpf(1.f + __expf(-x));
}
__device__ inline float softplusf_(float x) {
  return fmaxf(x, 0.f) + __logf(1.f + __expf(-fabsf(x)));
}

// ---------------- CSR build ----------------
__global__ __launch_bounds__(256) void hist_k(const int* __restrict__ ei,
                                              int* __restrict__ deg) {
  int e = blockIdx.x * 256 + threadIdx.x;
  if (e >= N_EDGES) return;
  atomicAdd(&deg[ei[N_EDGES + e]], 1);
}

__global__ __launch_bounds__(256) void scan1_k(const int* __restrict__ deg,
                                               int* __restrict__ rowptr,
                                               int* __restrict__ bsums) {
  __shared__ int s[256];
  int i = blockIdx.x * 256 + threadIdx.x;
  int v = (i < N_NODES) ? deg[i] : 0;
  s[threadIdx.x] = v;
  __syncthreads();
  for (int off = 1; off < 256; off <<= 1) {
    int t = (threadIdx.x >= off) ? s[threadIdx.x - off] : 0;
    __syncthreads();
    s[threadIdx.x] += t;
    __syncthreads();
  }
  if (i < N_NODES) rowptr[i] = s[threadIdx.x] - v;  // exclusive
  if (threadIdx.x == 255) bsums[blockIdx.x] = s[255];
}

__global__ __launch_bounds__(512) void scan2_k(int* __restrict__ bsums) {
  __shared__ int s[512];
  int t = threadIdx.x;
  int v = (t < SCAN_BLOCKS) ? bsums[t] : 0;
  s[t] = v;
  __syncthreads();
  for (int off = 1; off < 512; off <<= 1) {
    int x = (t >= off) ? s[t - off] : 0;
    __syncthreads();
    s[t] += x;
    __syncthreads();
  }
  if (t < SCAN_BLOCKS) bsums[t] = s[t] - v;  // exclusive
}

__global__ __launch_bounds__(256) void scan3_k(int* __restrict__ rowptr,
                                               const int* __restrict__ bsums,
                                               int* __restrict__ cur) {
  int i = blockIdx.x * 256 + threadIdx.x;
  if (i < N_NODES) {
    int r = rowptr[i] + bsums[blockIdx.x];
    rowptr[i] = r;
    cur[i] = r;
  }
  if (i == 0) rowptr[N_NODES] = N_EDGES;
}

// csr entry: {src, e, dst, 0}
__global__ __launch_bounds__(256) void scatter_k(const int* __restrict__ ei,
                                                 int* __restrict__ cur,
                                                 uint4* __restrict__ csr) {
  int e = blockIdx.x * 256 + threadIdx.x;
  if (e >= N_EDGES) return;
  int d = ei[N_EDGES + e];
  int pos = atomicAdd(&cur[d], 1);
  csr[pos] = make_uint4((uint)ei[e], (uint)e, (uint)d, 0u);
}

// ---------------- conv1 (channels=3) ----------------
__global__ __launch_bounds__(256) void conv1_edge(
    const float* __restrict__ x, const int* __restrict__ ei,
    const float* __restrict__ ea,
    const float* __restrict__ Wf, const float* __restrict__ bf,
    const float* __restrict__ Ws, const float* __restrict__ bs,
    float* __restrict__ agg1) {
  int e = blockIdx.x * 256 + threadIdx.x;
  if (e >= N_EDGES) return;
  int src = ei[e], dst = ei[N_EDGES + e];
  float z[38];
#pragma unroll
  for (int k = 0; k < 3; ++k) z[k] = x[dst * 3 + k];
#pragma unroll
  for (int k = 0; k < 3; ++k) z[3 + k] = x[src * 3 + k];
  const float4* er4 = (const float4*)(ea + (long long)e * 32);
#pragma unroll
  for (int k = 0; k < 8; ++k) {
    float4 v = er4[k];
    z[6 + 4 * k + 0] = v.x;
    z[6 + 4 * k + 1] = v.y;
    z[6 + 4 * k + 2] = v.z;
    z[6 + 4 * k + 3] = v.w;
  }
#pragma unroll
  for (int c = 0; c < 3; ++c) {
    float f = bf[c], s = bs[c];
#pragma unroll
    for (int k = 0; k < 38; ++k) {
      f = fmaf(z[k], Wf[k * 3 + c], f);
      s = fmaf(z[k], Ws[k * 3 + c], s);
    }
    atomicAdd(&agg1[dst * 3 + c], sigmoidf_(f) * softplusf_(s));
  }
}

// ---------------- projection: h = relu((x+agg1) @ Wp + bp) ----------------
__global__ __launch_bounds__(256) void proj_kernel(
    const float* __restrict__ x, const float* __restrict__ agg1,
    const float* __restrict__ Wp, const float* __restrict__ bp,
    float* __restrict__ h) {
  long long i = (long long)blockIdx.x * 256 + threadIdx.x;
  if (i >= (long long)N_NODES * HID) return;
  int n = (int)(i >> 7), j = (int)(i & 127);
  float v0 = x[n * 3 + 0] + agg1[n * 3 + 0];
  float v1 = x[n * 3 + 1] + agg1[n * 3 + 1];
  float v2 = x[n * 3 + 2] + agg1[n * 3 + 2];
  float acc = bp[j];
  acc = fmaf(v0, Wp[0 * HID + j], acc);
  acc = fmaf(v1, Wp[1 * HID + j], acc);
  acc = fmaf(v2, Wp[2 * HID + j], acc);
  h[i] = fmaxf(acc, 0.f);
}

#define BM 64
#define BK 32

// ---------------- NEW: node gates, packed {f,s} per channel ----------------
// Pb[node][256 dwords]: [0..127] = {f_dst, s_dst} per ch; [128..255] = {f_src, s_src}
__global__ __launch_bounds__(256) void node_gemm2(
    const float* __restrict__ h, const float* __restrict__ Wf,
    const float* __restrict__ Ws, uint* __restrict__ Pb) {
  __shared__ float As[BK][BM + 4];
  __shared__ float BfS[BK][BM + 4];
  __shared__ float BsS[BK][BM + 4];
  int jblk = blockIdx.x;            // 0..3
  int part = jblk >> 1;             // 0 dst, 1 src
  int colbase = (jblk & 1) * 64;
  int rowoff = part * 128;
  int m0 = blockIdx.y * BM;
  int tid = threadIdx.x, tx = tid & 15, ty = tid >> 4;
  float accF[4][4] = {}, accS[4][4] = {};
  for (int k0 = 0; k0 < 128; k0 += BK) {
#pragma unroll
    for (int i = 0; i < 2; ++i) {
      int f = tid + i * 256;
      int r = f >> 3, c4 = (f & 7) * 4;
      float4 v = {0.f, 0.f, 0.f, 0.f};
      int row = m0 + r;
      if (row < N_NODES)
        v = *(const float4*)&h[(long long)row * 128 + k0 + c4];
      As[c4 + 0][r] = v.x; As[c4 + 1][r] = v.y;
      As[c4 + 2][r] = v.z; As[c4 + 3][r] = v.w;
    }
#pragma unroll
    for (int i = 0; i < 2; ++i) {
      int f = tid + i * 256;
      int r = f >> 4, c4 = (f & 15) * 4;
      *(float4*)&BfS[r][c4] =
          *(const float4*)&Wf[(long long)(k0 + r + rowoff) * 128 + colbase + c4];
      *(float4*)&BsS[r][c4] =
          *(const float4*)&Ws[(long long)(k0 + r + rowoff) * 128 + colbase + c4];
    }
    __syncthreads();
#pragma unroll
    for (int k = 0; k < BK; ++k) {
      float4 a = *(const float4*)&As[k][ty * 4];
      float4 bF = *(const float4*)&BfS[k][tx * 4];
      float4 bS = *(const float4*)&BsS[k][tx * 4];
      float av[4] = {a.x, a.y, a.z, a.w};
      float bFv[4] = {bF.x, bF.y, bF.z, bF.w};
      float bSv[4] = {bS.x, bS.y, bS.z, bS.w};
#pragma unroll
      for (int i = 0; i < 4; ++i)
#pragma unroll
        for (int j = 0; j < 4; ++j) {
          accF[i][j] = fmaf(av[i], bFv[j], accF[i][j]);
          accS[i][j] = fmaf(av[i], bSv[j], accS[i][j]);
        }
    }
    __syncthreads();
  }
#pragma unroll
  for (int i = 0; i < 4; ++i) {
    int row = m0 + ty * 4 + i;
    if (row < N_NODES) {
      uint4 o;
      o.x = pack_bf16_2(accF[i][0], accS[i][0]);
      o.y = pack_bf16_2(accF[i][1], accS[i][1]);
      o.z = pack_bf16_2(accF[i][2], accS[i][2]);
      o.w = pack_bf16_2(accF[i][3], accS[i][3]);
      *(uint4*)&Pb[(long long)row * 256 + part * 128 + colbase + tx * 4] = o;
    }
  }
}

// ---- OLD node_gemm (sectioned layout) for fallback path ----
__global__ __launch_bounds__(256) void node_gemm(
    const float* __restrict__ h, const float* __restrict__ Wf,
    const float* __restrict__ Ws, uint* __restrict__ Pb) {
  __shared__ float As[BK][BM + 4];
  __shared__ float Bs[BK][BM + 4];
  int jblk = blockIdx.x;
  int sec = jblk >> 1;
  int colbase = (jblk & 1) * 64;
  const float* W = (sec == 0 || sec == 2) ? Wf : Ws;
  int rowoff = (sec >= 2) ? 128 : 0;
  int m0 = blockIdx.y * BM;
  int tid = threadIdx.x;
  int tx = tid & 15, ty = tid >> 4;
  float acc[4][4] = {};
  for (int k0 = 0; k0 < 128; k0 += BK) {
#pragma unroll
    for (int i = 0; i < 2; ++i) {
      int f = tid + i * 256;
      int r = f >> 3, c4 = (f & 7) * 4;
      float4 v = {0.f, 0.f, 0.f, 0.f};
      int row = m0 + r;
      if (row < N_NODES)
        v = *(const float4*)&h[(long long)row * 128 + k0 + c4];
      As[c4 + 0][r] = v.x; As[c4 + 1][r] = v.y;
      As[c4 + 2][r] = v.z; As[c4 + 3][r] = v.w;
    }
#pragma unroll
    for (int i = 0; i < 2; ++i) {
      int f = tid + i * 256;
      int r = f >> 4, c4 = (f & 15) * 4;
      float4 v = *(const float4*)&W[(long long)(k0 + r + rowoff) * 128 + colbase + c4];
      *(float4*)&Bs[r][c4] = v;
    }
    __syncthreads();
#pragma unroll
    for (int k = 0; k < BK; ++k) {
      float4 a = *(const float4*)&As[k][ty * 4];
      float4 b = *(const float4*)&Bs[k][tx * 4];
      float av[4] = {a.x, a.y, a.z, a.w};
      float bv[4] = {b.x, b.y, b.z, b.w};
#pragma unroll
      for (int i = 0; i < 4; ++i)
#pragma unroll
        for (int j = 0; j < 4; ++j)
          acc[i][j] = fmaf(av[i], bv[j], acc[i][j]);
    }
    __syncthreads();
  }
#pragma unroll
  for (int i = 0; i < 4; ++i) {
    int row = m0 + ty * 4 + i;
    if (row < N_NODES) {
      uint2 o;
      o.x = pack_bf16_2(acc[i][0], acc[i][1]);
      o.y = pack_bf16_2(acc[i][2], acc[i][3]);
      *(uint2*)&Pb[(long long)row * 256 + jblk * 32 + tx * 2] = o;
    }
  }
}

// ---- w_prep: Btg[ch 0..255][16 dwords] = bf16{W[256+2k][c], W[256+2k+1][c]} ----
// ch 0..127 -> Wf columns (f), 128..255 -> Ws columns (s). One block.
__global__ __launch_bounds__(256) void w_prep(const float* __restrict__ Wf,
                                              const float* __restrict__ Ws,
                                              uint* __restrict__ Btg) {
  int t = threadIdx.x;
  const float* W = (t < 128) ? Wf : Ws;
  int c = t & 127;
#pragma unroll
  for (int kk = 0; kk < 16; ++kk) {
    float a = W[(256 + 2 * kk) * 128 + c];
    float b = W[(256 + 2 * kk + 1) * 128 + c];
    Btg[t * 16 + kk] = pack_bf16_2(a, b);
  }
}

// ---- edge_msg: MFMA edge-gemm + gates + activations -> m (bf16 pairs) ----
// Per block: 64 CSR-consecutive edges. m layout: mb[j>>1][128 ch] dwords,
// lo = m(even j), hi = m(odd j).
#define EMSG_EB 64
__global__ __launch_bounds__(256, 4) void edge_msg(
    const uint* __restrict__ Pb, const float* __restrict__ ea,
    const uint* __restrict__ Btg,
    const float* __restrict__ bf, const float* __restrict__ bs,
    const uint4* __restrict__ csr, uint* __restrict__ mb) {
  __shared__ uint Alds[EMSG_EB * 16];   // [edge][16 dwords] bf16 pairs along k
  __shared__ uint Blds[256 * 16];       // [ch][16 dwords]
  int tid = threadIdx.x;
  int j0 = blockIdx.x * EMSG_EB;
  // stage B (16 KB)
  {
    const uint4* s4 = (const uint4*)(Btg + tid * 16);
    uint4 v0 = s4[0], v1 = s4[1], v2 = s4[2], v3 = s4[3];
    uint4* d4 = (uint4*)&Blds[tid * 16];
    d4[0] = v0; d4[1] = v1; d4[2] = v2; d4[3] = v3;
  }
  // stage A: 4 threads per edge row, 8 floats each -> bf16 pairs
  {
    int r = tid >> 2, q = tid & 3;
    uint e = csr[j0 + r].y;
    const float4* er = (const float4*)(ea + (long long)e * 32 + q * 8);
    float4 a0 = er[0], a1 = er[1];
    uint4 pk;
    pk.x = pack_bf16_2(a0.x, a0.y);
    pk.y = pack_bf16_2(a0.z, a0.w);
    pk.z = pack_bf16_2(a1.x, a1.y);
    pk.w = pack_bf16_2(a1.z, a1.w);
    *(uint4*)&Alds[r * 16 + q * 4] = pk;
  }
  __syncthreads();
  int wave = tid >> 6, lane = tid & 63;
  int c0w = wave * 32;           // 32 channels per wave
  int l15 = lane & 15, lq = lane >> 4;
  bf16x8 afr[4], bfr[4];
#pragma unroll
  for (int mt = 0; mt < 4; ++mt)
    afr[mt] = *(const bf16x8*)&Alds[(mt * 16 + l15) * 16 + lq * 4];
  // B tiles: {f c0w+0..15, f c0w+16..31, s c0w+0..15, s c0w+16..31}
  int chs0 = c0w + l15, chs1 = c0w + 16 + l15;
  bfr[0] = *(const bf16x8*)&Blds[chs0 * 16 + lq * 4];
  bfr[1] = *(const bf16x8*)&Blds[chs1 * 16 + lq * 4];
  bfr[2] = *(const bf16x8*)&Blds[(128 + chs0) * 16 + lq * 4];
  bfr[3] = *(const bf16x8*)&Blds[(128 + chs1) * 16 + lq * 4];
  f32x4 acc[4][4];
#pragma unroll
  for (int mt = 0; mt < 4; ++mt)
#pragma unroll
    for (int nt = 0; nt < 4; ++nt) {
      f32x4 z = {0.f, 0.f, 0.f, 0.f};
      acc[mt][nt] = __builtin_amdgcn_mfma_f32_16x16x32_bf16(afr[mt], bfr[nt], z, 0, 0, 0);
    }
  float bf0 = bf[chs0], bf1 = bf[chs1];
  float bs0 = bs[chs0], bs1 = bs[chs1];
  // epilogue: C layout col=lane&15 (ch), row=(lane>>4)*4+reg (edge)
#pragma unroll
  for (int mt = 0; mt < 4; ++mt) {
    int jb = j0 + mt * 16 + lq * 4;
    uint srcs[4], dsts[4];
#pragma unroll
    for (int reg = 0; reg < 4; ++reg) {
      uint4 cj = csr[jb + reg];
      srcs[reg] = cj.x;
      dsts[reg] = cj.z;
    }
#pragma unroll
    for (int cp = 0; cp < 2; ++cp) {
      int c = (cp ? chs1 : chs0);
      float bfv = cp ? bf1 : bf0;
      float bsv = cp ? bs1 : bs0;
      float mr[4];
#pragma unroll
      for (int reg = 0; reg < 4; ++reg) {
        uint gd = Pb[(long long)dsts[reg] * 256 + c];
        uint gs = Pb[(long long)srcs[reg] * 256 + 128 + c];
        float f = acc[mt][cp][reg] + bflo(gd) + bflo(gs) + bfv;
        float s = acc[mt][2 + cp][reg] + bfhi(gd) + bfhi(gs) + bsv;
        mr[reg] = sigmoidf_(f) * softplusf_(s);
      }
      int jp = jb >> 1;  // jb is even (j0, mt*16, lq*4 all even)
      mb[(long long)jp * 128 + c] = pack_bf16_2(mr[0], mr[1]);
      mb[(long long)(jp + 1) * 128 + c] = pack_bf16_2(mr[2], mr[3]);
    }
  }
}

// ---- agg_sum: h[node][c] = relu(h + sum_j m[j][c]) ----
__global__ __launch_bounds__(256, 8) void agg_sum(
    const uint* __restrict__ mb, const int* __restrict__ rowptr,
    float* __restrict__ h) {
  int wave = threadIdx.x >> 6;
  int lane = threadIdx.x & 63;
  int c = ((wave & 1) << 6) + lane;
  int nodeSlot = wave >> 1;
  for (int node = blockIdx.x * 2 + nodeSlot; node < N_NODES;
       node += gridDim.x * 2) {
    int row0 = rowptr[node], row1 = rowptr[node + 1];
    float a = 0.f;
    int j = row0;
    if (j < row1 && (j & 1)) {
      a += bfhi(mb[(long long)(j >> 1) * 128 + c]);
      ++j;
    }
    for (; j + 3 < row1; j += 4) {
      uint d0 = mb[(long long)(j >> 1) * 128 + c];
      uint d1 = mb[(long long)((j >> 1) + 1) * 128 + c];
      a += bflo(d0) + bfhi(d0);
      a += bflo(d1) + bfhi(d1);
    }
    for (; j + 1 < row1; j += 2) {
      uint d0 = mb[(long long)(j >> 1) * 128 + c];
      a += bflo(d0) + bfhi(d0);
    }
    if (j < row1) a += bflo(mb[(long long)(j >> 1) * 128 + c]);
    float* hp = &h[(long long)node * HID + c];
    *hp = fmaxf(*hp + a, 0.f);
  }
}

// -------- fallback: fused CSR aggregation (old VALU path) --------
__global__ __launch_bounds__(256, 4) void agg_fused(
    const uint* __restrict__ Pb, const float* __restrict__ ea,
    const float* __restrict__ Wf, const float* __restrict__ Ws,
    const float* __restrict__ bf, const float* __restrict__ bs,
    const int* __restrict__ rowptr, const uint4* __restrict__ csr,
    float* __restrict__ h) {
  int wave = threadIdx.x >> 6;
  int lane = threadIdx.x & 63;
  int c = ((wave & 1) << 6) + lane;
  int nodeSlot = wave >> 1;
  float wf[32], ws[32];
#pragma unroll
  for (int k = 0; k < 32; ++k) {
    wf[k] = Wf[(256 + k) * HID + c];
    ws[k] = Ws[(256 + k) * HID + c];
  }
  float bfc = bf[c], bsc = bs[c];
  int dw = c >> 1;
  uint shamt = (c & 1) ? 0u : 16u;
  for (int node = blockIdx.x * 2 + nodeSlot; node < N_NODES;
       node += gridDim.x * 2) {
    int row0 = rowptr[node], row1 = rowptr[node + 1];
    const uint* Pd = Pb + (long long)node * 256;
    uint fdu = Pd[dw], sdu = Pd[64 + dw];
    float fd = bfsel(fdu, shamt) + bfc;
    float sd = bfsel(sdu, shamt) + bsc;
    float a = 0.f;
    int j = row0;
    for (; j + 1 < row1; j += 2) {
      uint4 m0 = csr[j], m1 = csr[j + 1];
      int sA = __builtin_amdgcn_readfirstlane((int)m0.x);
      int eA = __builtin_amdgcn_readfirstlane((int)m0.y);
      int sB = __builtin_amdgcn_readfirstlane((int)m1.x);
      int eB = __builtin_amdgcn_readfirstlane((int)m1.y);
      const float* erA = ea + (long long)eA * 32;
      const float* erB = ea + (long long)eB * 32;
      const uint* PsA = Pb + (long long)sA * 256;
      const uint* PsB = Pb + (long long)sB * 256;
      uint fsuA = PsA[128 + dw], ssuA = PsA[192 + dw];
      uint fsuB = PsB[128 + dw], ssuB = PsB[192 + dw];
      float efA = 0.f, esA = 0.f, efB = 0.f, esB = 0.f;
#pragma unroll
      for (int k = 0; k < 32; ++k) {
        float evA = erA[k], evB = erB[k];
        efA = fmaf(evA, wf[k], efA);
        esA = fmaf(evA, ws[k], esA);
        efB = fmaf(evB, wf[k], efB);
        esB = fmaf(evB, ws[k], esB);
      }
      float fA = fd + bfsel(fsuA, shamt) + efA;
      float gA = sd + bfsel(ssuA, shamt) + esA;
      float fB = fd + bfsel(fsuB, shamt) + efB;
      float gB = sd + bfsel(ssuB, shamt) + esB;
      a += sigmoidf_(fA) * softplusf_(gA);
      a += sigmoidf_(fB) * softplusf_(gB);
    }
    if (j < row1) {
      uint4 m0 = csr[j];
      int sA = __builtin_amdgcn_readfirstlane((int)m0.x);
      int eA = __builtin_amdgcn_readfirstlane((int)m0.y);
      const float* erA = ea + (long long)eA * 32;
      const uint* PsA = Pb + (long long)sA * 256;
      uint fsuA = PsA[128 + dw], ssuA = PsA[192 + dw];
      float efA = 0.f, esA = 0.f;
#pragma unroll
      for (int k = 0; k < 32; ++k) {
        float evA = erA[k];
        efA = fmaf(evA, wf[k], efA);
        esA = fmaf(evA, ws[k], esA);
      }
      float fA = fd + bfsel(fsuA, shamt) + efA;
      float gA = sd + bfsel(ssuA, shamt) + esA;
      a += sigmoidf_(fA) * softplusf_(gA);
    }
    float* hp = &h[(long long)node * HID + c];
    *hp = fmaxf(*hp + a, 0.f);
  }
}

// -------- segmented mean pool (batch sorted) --------
#define POOL_NODES 128
__global__ __launch_bounds__(128) void pool2(
    const float* __restrict__ h, const int* __restrict__ batch,
    float* __restrict__ sums, float* __restrict__ cnts) {
  int n0 = blockIdx.x * POOL_NODES;
  if (n0 >= N_NODES) return;
  int t = threadIdx.x;
  int nEnd = n0 + POOL_NODES;
  if (nEnd > N_NODES) nEnd = N_NODES;
  float acc = 0.f;
  int bcur = batch[n0];
  int cnt = 0;
  for (int n = n0; n < nEnd; ++n) {
    int b = batch[n];
    if (b != bcur) {
      atomicAdd(&sums[bcur * HID + t], acc);
      if (t == 0) atomicAdd(&cnts[bcur], (float)cnt);
      acc = 0.f; cnt = 0; bcur = b;
    }
    acc += h[(long long)n * HID + t];
    ++cnt;
  }
  atomicAdd(&sums[bcur * HID + t], acc);
  if (t == 0) atomicAdd(&cnts[bcur], (float)cnt);
}

// ---------------- graph MLP ----------------
__global__ __launch_bounds__(128) void mlpA(
    const float* __restrict__ sums, const float* __restrict__ cnts,
    const float* __restrict__ W1, const float* __restrict__ b1,
    float* __restrict__ g) {
  __shared__ float pl[HID];
  int gr = blockIdx.x, j = threadIdx.x;
  float cnt = fmaxf(cnts[gr], 1.f);
  pl[j] = sums[gr * HID + j] / cnt;
  __syncthreads();
  float acc = b1[j];
#pragma unroll 8
  for (int k = 0; k < HID; ++k) acc = fmaf(pl[k], W1[k * HID + j], acc);
  g[gr * HID + j] = fmaxf(acc, 0.f);
}

__global__ __launch_bounds__(256) void mlpB(
    const float* __restrict__ g, const float* __restrict__ W2,
    const float* __restrict__ b2, float* __restrict__ out) {
  int t = threadIdx.x;
  if (t >= 64 * 3) return;
  int gr = t / 3, o = t % 3;
  float acc = b2[o];
#pragma unroll 8
  for (int k = 0; k < HID; ++k) acc = fmaf(g[gr * HID + k], W2[k * 3 + o], acc);
  out[t] = acc;
}

extern "C" void kernel_launch(void* const* d_in, const int* in_sizes, int n_in,
                              void* d_out, int out_size, void* d_ws, size_t ws_size,
                              hipStream_t stream) {
  const float* x   = (const float*)d_in[0];
  const int*   ei  = (const int*)d_in[1];
  const float* ea  = (const float*)d_in[2];
  const int*   bat = (const int*)d_in[3];
  const float* Wf1 = (const float*)d_in[4];
  const float* bf1 = (const float*)d_in[5];
  const float* Ws1 = (const float*)d_in[6];
  const float* bs1 = (const float*)d_in[7];
  const float* Wp  = (const float*)d_in[8];
  const float* bp  = (const float*)d_in[9];
  const float* Wf2 = (const float*)d_in[10];
  const float* bf2 = (const float*)d_in[11];
  const float* Ws2 = (const float*)d_in[12];
  const float* bs2 = (const float*)d_in[13];
  const float* Wf3 = (const float*)d_in[14];
  const float* bf3 = (const float*)d_in[15];
  const float* Ws3 = (const float*)d_in[16];
  const float* bs3 = (const float*)d_in[17];
  const float* W1  = (const float*)d_in[18];
  const float* b1  = (const float*)d_in[19];
  const float* W2  = (const float*)d_in[20];
  const float* b2  = (const float*)d_in[21];
  float* out = (float*)d_out;

  char* w = (char*)d_ws;
  size_t off = 0;
  auto alloc = [&](size_t bytes) {
    void* p = w + off;
    off += (bytes + 255) & ~(size_t)255;
    return p;
  };
  int*   deg    = (int*)alloc((size_t)N_NODES * 4);
  int*   rowptr = (int*)alloc((size_t)(N_NODES + 1) * 4);
  int*   cur    = (int*)alloc((size_t)N_NODES * 4);
  int*   bsums  = (int*)alloc((size_t)512 * 4);
  uint4* csr    = (uint4*)alloc((size_t)N_EDGES * 16);       // 25.6 MB
  float* agg1   = (float*)alloc((size_t)N_NODES * 3 * 4);    // 1.2 MB
  float* h      = (float*)alloc((size_t)N_NODES * HID * 4);  // 51.2 MB
  uint*  Pb     = (uint*)alloc((size_t)N_NODES * 256 * 4);   // 102.4 MB
  float* sums   = (float*)alloc((size_t)64 * HID * 4);
  float* cnts   = (float*)alloc((size_t)64 * 4);
  float* g      = (float*)alloc((size_t)64 * HID * 4);
  uint*  Btg    = (uint*)alloc((size_t)256 * 16 * 4);        // 16 KB
  // m buffer (new path only): 800000 pair-rows x 128 dwords = 409.6 MB
  size_t mb_bytes = (size_t)(N_EDGES / 2) * 128 * 4;
  bool newpath = (off + mb_bytes + 256) <= ws_size;
  uint* mb = (uint*)(w + off);

  // ---- CSR build ----
  hipMemsetAsync(deg, 0, (size_t)N_NODES * 4, stream);
  hist_k<<<(N_EDGES + 255) / 256, 256, 0, stream>>>(ei, deg);
  scan1_k<<<SCAN_BLOCKS, 256, 0, stream>>>(deg, rowptr, bsums);
  scan2_k<<<1, 512, 0, stream>>>(bsums);
  scan3_k<<<SCAN_BLOCKS, 256, 0, stream>>>(rowptr, bsums, cur);
  scatter_k<<<(N_EDGES + 255) / 256, 256, 0, stream>>>(ei, cur, csr);

  // ---- conv1 ----
  hipMemsetAsync(agg1, 0, (size_t)N_NODES * 3 * 4, stream);
  conv1_edge<<<(N_EDGES + 255) / 256, 256, 0, stream>>>(x, ei, ea, Wf1, bf1, Ws1, bs1, agg1);
  proj_kernel<<<(N_NODES * HID + 255) / 256, 256, 0, stream>>>(x, agg1, Wp, bp, h);

  if (newpath) {
    dim3 ngrid2(4, (N_NODES + BM - 1) / BM);
    int eblocks = N_EDGES / EMSG_EB;  // 25000, exact
    // ---- conv2 ----
    node_gemm2<<<ngrid2, 256, 0, stream>>>(h, Wf2, Ws2, Pb);
    w_prep<<<1, 256, 0, stream>>>(Wf2, Ws2, Btg);
    edge_msg<<<eblocks, 256, 0, stream>>>(Pb, ea, Btg, bf2, bs2, csr, mb);
    agg_sum<<<8192, 256, 0, stream>>>(mb, rowptr, h);
    // ---- conv3 ----
    node_gemm2<<<ngrid2, 256, 0, stream>>>(h, Wf3, Ws3, Pb);
    w_prep<<<1, 256, 0, stream>>>(Wf3, Ws3, Btg);
    edge_msg<<<eblocks, 256, 0, stream>>>(Pb, ea, Btg, bf3, bs3, csr, mb);
    agg_sum<<<8192, 256, 0, stream>>>(mb, rowptr, h);
  } else {
    dim3 ngrid(8, (N_NODES + BM - 1) / BM);
    // ---- conv2 ----
    node_gemm<<<ngrid, 256, 0, stream>>>(h, Wf2, Ws2, Pb);
    agg_fused<<<AGGF_BLOCKS, 256, 0, stream>>>(Pb, ea, Wf2, Ws2, bf2, bs2, rowptr, csr, h);
    // ---- conv3 ----
    node_gemm<<<ngrid, 256, 0, stream>>>(h, Wf3, Ws3, Pb);
    agg_fused<<<AGGF_BLOCKS, 256, 0, stream>>>(Pb, ea, Wf3, Ws3, bf3, bs3, rowptr, csr, h);
  }

  // ---- pool + MLP ----
  hipMemsetAsync(sums, 0, (size_t)(64 * HID + 64) * 4, stream);
  pool2<<<(N_NODES + POOL_NODES - 1) / POOL_NODES, POOL_NODES, 0, stream>>>(h, bat, sums, cnts);
  mlpA<<<64, 128, 0, stream>>>(sums, cnts, W1, b1, g);
  mlpB<<<1, 256, 0, stream>>>(g, W2, b2, out);
}